// Round 1
// baseline (449.714 us; speedup 1.0000x reference)
//
#include <hip/hip_runtime.h>
#include <hip/hip_bf16.h>

// GraphAttentionLayer: B=4, N=4096, F=64
// h = inp@W; lh = lrelu(h,.2); fsrc = lh@a[:64]; fdst = lh@a[64:]
// dj = 0.8*adj[i][j] + 0.2*(fsrc[i]+fdst[j]); E = dj>0 ? exp(dj) : 0  (dj<=~3.3, no max needed)
// s[j] = sum_i E[i][j];  out[i][o] = relu( sum_j E[i][j] * (h[j][o]/s[j]) )

#define Bn 4
#define Nn 4096
#define KS 4    // K-split in attnmm
#define IC 64   // i-chunks in estats

typedef _Float16 half8 __attribute__((ext_vector_type(8)));
typedef _Float16 half4 __attribute__((ext_vector_type(4)));
typedef float f32x4 __attribute__((ext_vector_type(4)));
typedef float f4v __attribute__((ext_vector_type(4)));

__global__ __launch_bounds__(256) void k_prep(
    const float* __restrict__ inp, const float* __restrict__ W,
    const float* __restrict__ a, float* __restrict__ h,
    float* __restrict__ fsrc, float* __restrict__ fdst) {
  __shared__ float Ws[64 * 64];
  __shared__ float as[128];
  __shared__ float xs[4][64];
  const int t = threadIdx.x;
  for (int k = t; k < 4096; k += 256) Ws[k] = W[k];
  if (t < 128) as[t] = a[t];
  const int w = t >> 6;
  const int o = t & 63;
  const int row = blockIdx.x * 4 + w;
  xs[w][o] = inp[(size_t)row * 64 + o];
  __syncthreads();
  float acc = 0.f;
  const float* xr = xs[w];
#pragma unroll
  for (int f = 0; f < 64; ++f) acc += xr[f] * Ws[f * 64 + o];
  h[(size_t)row * 64 + o] = acc;
  float lh = acc > 0.f ? acc : 0.2f * acc;
  float vs = lh * as[o];
  float vd = lh * as[64 + o];
#pragma unroll
  for (int off = 32; off > 0; off >>= 1) {
    vs += __shfl_down(vs, off);
    vd += __shfl_down(vd, off);
  }
  if (o == 0) { fsrc[row] = vs; fdst[row] = vd; }
}

// Single pass over adj: E = fp16(masked exp); per-chunk column partial sums.
// adj is read ONCE and harness-restored next iter -> non-temporal loads keep
// it out of L3 so the freshly written E (134 MB) stays L3-resident for attnmm.
// grid (jb=4, ic=64, b=4) = 1024 blocks; block 256; thread owns 4 consecutive j.
__global__ __launch_bounds__(256) void k_estats(
    const float* __restrict__ adj, const float* __restrict__ fsrc,
    const float* __restrict__ fdst, _Float16* __restrict__ E,
    float* __restrict__ pm) {
  const int t = threadIdx.x;
  const int jb = blockIdx.x, ic = blockIdx.y, b = blockIdx.z;
  const int j = jb * 1024 + t * 4;
  const int i0 = ic * 64;
  __shared__ float fss[64];
  if (t < 64) fss[t] = fsrc[b * Nn + i0 + t];
  __syncthreads();
  const float4 fd = *(const float4*)&fdst[b * Nn + j];
  const f4v* ap = (const f4v*)(adj + ((size_t)(b * Nn + i0)) * Nn + j);
  _Float16* ep = E + ((size_t)(b * Nn + i0)) * Nn + j;
  float s0 = 0.f, s1 = 0.f, s2 = 0.f, s3 = 0.f;
#pragma unroll 4
  for (int ii = 0; ii < 64; ++ii) {
    f4v v = __builtin_nontemporal_load(ap + (size_t)ii * 1024);
    float fi = fss[ii];
    float d0 = 0.8f * v.x + 0.2f * (fi + fd.x);
    float d1 = 0.8f * v.y + 0.2f * (fi + fd.y);
    float d2 = 0.8f * v.z + 0.2f * (fi + fd.z);
    float d3 = 0.8f * v.w + 0.2f * (fi + fd.w);
    float e0 = d0 > 0.f ? __expf(d0) : 0.f;
    float e1 = d1 > 0.f ? __expf(d1) : 0.f;
    float e2 = d2 > 0.f ? __expf(d2) : 0.f;
    float e3 = d3 > 0.f ? __expf(d3) : 0.f;
    s0 += e0; s1 += e1; s2 += e2; s3 += e3;
    half4 e;
    e[0] = (_Float16)e0; e[1] = (_Float16)e1;
    e[2] = (_Float16)e2; e[3] = (_Float16)e3;
    *(half4*)(ep + (size_t)ii * Nn) = e;
  }
  float4 sv; sv.x = s0; sv.y = s1; sv.z = s2; sv.w = s3;
  *(float4*)&pm[((size_t)(ic * Bn + b)) * Nn + j] = sv;
}

// Reduce pm over ic, then hT[b][o][j] = fp16( h[b][j][o] / s[j] ).
// grid (jt=64, b=4), block 256.
__global__ __launch_bounds__(256) void k_hscale(
    const float* __restrict__ h, const float* __restrict__ pm,
    _Float16* __restrict__ hT) {
  const int t = threadIdx.x;
  const int jt = blockIdx.x, b = blockIdx.y;
  __shared__ _Float16 hl[64][72];
  __shared__ float sis[64];
  if (t < 64) {
    const int j = jt * 64 + t;
    float sv = 0.f;
#pragma unroll 8
    for (int ic = 0; ic < IC; ++ic) sv += pm[((size_t)(ic * Bn + b)) * Nn + j];
    sis[t] = sv > 0.f ? 1.0f / sv : 0.f;   // all-masked column contributes 0
  }
  __syncthreads();
#pragma unroll
  for (int r = 0; r < 4; ++r) {
    const int jl = r * 16 + (t >> 4);
    const int j = jt * 64 + jl;
    const int o4 = (t & 15) * 4;
    float si = sis[jl];
    float4 hv = *(const float4*)&h[((size_t)(b * Nn + j)) * 64 + o4];
    hl[o4 + 0][jl] = (_Float16)(hv.x * si);
    hl[o4 + 1][jl] = (_Float16)(hv.y * si);
    hl[o4 + 2][jl] = (_Float16)(hv.z * si);
    hl[o4 + 3][jl] = (_Float16)(hv.w * si);
  }
  __syncthreads();
#pragma unroll
  for (int r = 0; r < 2; ++r) {
    const int o = r * 32 + (t >> 3);
    const int ch = t & 7;
    half8 v = *(half8*)&hl[o][ch * 8];
    *(half8*)&hT[((size_t)(b * 64 + o)) * 4096 + jt * 64 + ch * 8] = v;
  }
}

// part = E @ hT, K-split x4. grid (ks=4, ib=32, b=4) = 512 blocks (2/CU),
// block 256 (4 waves). Block: 128 i x 64 o, K-slice 1024.
// BARRIER-FREE: hT is 2 MB -> fully L2-resident, so the MFMA B-fragments are
// loaded straight from global into registers (identical lane layout to the
// old LDS path: row o = lane&15, k = (lane>>4)*8). No LDS, no __syncthreads;
// each wave owns 32 i rows (acc[2][4]) to halve redundant hT fragment reads.
// E read once -> non-temporal (L3-resident from k_estats).
__global__ __launch_bounds__(256) void k_attnmm(
    const _Float16* __restrict__ E, const _Float16* __restrict__ hT,
    float* __restrict__ part) {
  const int t = threadIdx.x;
  const int ks = blockIdx.x;   // 0..KS-1
  const int ib = blockIdx.y;   // 0..31
  const int b = blockIdx.z;
  const int w = t >> 6;
  const int lane = t & 63;

  const int i0 = ib * 128 + w * 32;      // this wave's 32 output rows
  const int kbase = ks * (Nn / KS);      // 1024-wide K slice
  const int rlane = lane & 15;
  const int klane = (lane >> 4) * 8;     // 0,8,16,24

  f32x4 acc[2][4];
#pragma unroll
  for (int m = 0; m < 2; ++m)
#pragma unroll
    for (int n = 0; n < 4; ++n)
#pragma unroll
      for (int r = 0; r < 4; ++r) acc[m][n][r] = 0.f;

  const _Float16* Ep0 = E + ((size_t)(b * Nn + i0 + rlane)) * Nn + kbase + klane;
  const _Float16* Ep1 = Ep0 + (size_t)16 * Nn;
  const _Float16* hp  = hT + ((size_t)(b * 64 + rlane)) * Nn + kbase + klane;

#pragma unroll 4
  for (int k = 0; k < Nn / KS; k += 32) {
    half8 af[2], bf[4];
    af[0] = __builtin_nontemporal_load((const half8*)(Ep0 + k));
    af[1] = __builtin_nontemporal_load((const half8*)(Ep1 + k));
#pragma unroll
    for (int n = 0; n < 4; ++n)
      bf[n] = *(const half8*)(hp + (size_t)(n * 16) * Nn + k);
#pragma unroll
    for (int m = 0; m < 2; ++m)
#pragma unroll
      for (int n = 0; n < 4; ++n)
        acc[m][n] = __builtin_amdgcn_mfma_f32_16x16x32_f16(af[m], bf[n], acc[m][n], 0, 0, 0);
  }

  // C/D layout: col = lane&15 (o), row = (lane>>4)*4 + r (i)
  const int r0 = (lane >> 4) * 4;
#pragma unroll
  for (int m = 0; m < 2; ++m)
#pragma unroll
    for (int n = 0; n < 4; ++n)
#pragma unroll
      for (int r = 0; r < 4; ++r) {
        const int i = i0 + m * 16 + r0 + r;
        const int o = n * 16 + rlane;
        part[(((size_t)ks * Bn + b) * Nn + i) * 64 + o] = acc[m][n][r];
      }
}

__global__ __launch_bounds__(256) void k_final(
    const float* __restrict__ part, float* __restrict__ out) {
  const int e = blockIdx.x * 256 + threadIdx.x;
  const f4v* p4 = (const f4v*)part;
  f4v sv = __builtin_nontemporal_load(p4 + e);
  const size_t stride = (size_t)Bn * Nn * 64 / 4;
#pragma unroll
  for (int ks = 1; ks < KS; ++ks) {
    f4v v = __builtin_nontemporal_load(p4 + (size_t)ks * stride + e);
    sv.x += v.x; sv.y += v.y; sv.z += v.z; sv.w += v.w;
  }
  float4 r;
  r.x = fmaxf(sv.x, 0.f); r.y = fmaxf(sv.y, 0.f);
  r.z = fmaxf(sv.z, 0.f); r.w = fmaxf(sv.w, 0.f);
  ((float4*)out)[e] = r;
}

extern "C" void kernel_launch(void* const* d_in, const int* in_sizes, int n_in,
                              void* d_out, int out_size, void* d_ws, size_t ws_size,
                              hipStream_t stream) {
  const float* inp = (const float*)d_in[0];   // [4,4096,64]
  const float* adj = (const float*)d_in[1];   // [4,4096,4096]
  const float* W   = (const float*)d_in[2];   // [64,64]
  const float* a   = (const float*)d_in[3];   // [128,1]
  float* out = (float*)d_out;                 // [4,4096,64]

  float* ws   = (float*)d_ws;
  float* h    = ws;                           // 1,048,576 f32 (4 MB)
  float* fsrc = h + 1048576;                  // 16,384
  float* fdst = fsrc + 16384;                 // 16,384
  float* pm   = fdst + 16384;                 // IC*Bn*Nn f32 (4 MB)
  float* part = pm + (size_t)IC * Bn * Nn;    // KS*Bn*Nn*64 f32 (16 MB)
  _Float16* hT = (_Float16*)(part + (size_t)KS * Bn * Nn * 64);  // 2 MB
  _Float16* E  = hT + (size_t)Bn * 64 * Nn;   // 4*4096*4096 f16 (134 MB)

  k_prep<<<Bn * Nn / 4, 256, 0, stream>>>(inp, W, a, h, fsrc, fdst);
  k_estats<<<dim3(4, IC, Bn), 256, 0, stream>>>(adj, fsrc, fdst, E, pm);
  k_hscale<<<dim3(64, Bn), 256, 0, stream>>>(h, pm, hT);
  k_attnmm<<<dim3(KS, 32, Bn), 256, 0, stream>>>(E, hT, part);
  k_final<<<Bn * Nn * 64 / 4 / 256, 256, 0, stream>>>(part, out);
}